// Round 1
// baseline (569.072 us; speedup 1.0000x reference)
//
#include <hip/hip_runtime.h>

#define BB 32
#define NN 4096
#define CC 256
#define KK 64
#define DD 256

// ---- workspace layout (in floats) ----
#define SA_OFF   ((size_t)0)                       // sa      [B][K][N]
#define INV_OFF  (SA_OFF  + (size_t)BB*KK*NN)      // invn    [B][N]
#define VP_OFF   (INV_OFF + (size_t)BB*NN)         // vpart   [B][16][K][C]
#define SP_OFF   (VP_OFF  + (size_t)BB*16*KK*CC)   // spart   [B][16][K]
#define VN_OFF   (SP_OFF  + (size_t)BB*16*KK)      // vladn   [B][K*C]
#define O1_OFF   (VN_OFF  + (size_t)BB*KK*CC)      // out1    [B][D]
#define K5_OFF   (O1_OFF  + (size_t)BB*DD)         // k5part  [256][B][D]

// ============================================================
// K1: per-token L2 norm + 1x1-conv logits + softmax over K
// block = 256 threads, 64 tokens; grid = B * N/64 = 2048
// ============================================================
__global__ __launch_bounds__(256) void k_softmax(
    const float* __restrict__ x, const float* __restrict__ conv_w,
    float* __restrict__ sa, float* __restrict__ invn) {
  __shared__ float xh[128][64];    // half of channels, [c][t]
  __shared__ float sal[64][65];    // logits [k][t]
  __shared__ float invls[64];

  const int tid = threadIdx.x;
  const int b  = blockIdx.x >> 6;
  const int n0 = (blockIdx.x & 63) * 64;

  const int lt = tid >> 2;       // token row 0..63
  const int lseg = tid & 3;      // 0..3
  const float4* xrow = reinterpret_cast<const float4*>(
      x + ((size_t)b * NN + n0 + lt) * CC);

  // ---- load half 0 into LDS, start ssq ----
  float4 r[8];
#pragma unroll
  for (int j = 0; j < 8; ++j) r[j] = xrow[lseg + 4 * j];
  float ssq = 0.f;
#pragma unroll
  for (int j = 0; j < 8; ++j) {
    float4 v = r[j];
    ssq += v.x * v.x + v.y * v.y + v.z * v.z + v.w * v.w;
    int c = (lseg + 4 * j) * 4;
    xh[c + 0][lt] = v.x; xh[c + 1][lt] = v.y;
    xh[c + 2][lt] = v.z; xh[c + 3][lt] = v.w;
  }
  __syncthreads();

  // issue half-1 global loads (latency hidden under logits-0 compute)
#pragma unroll
  for (int j = 0; j < 8; ++j) r[j] = xrow[32 + lseg + 4 * j];

  const int t = tid & 63;        // token
  const int q = tid >> 6;        // k-group 0..3 (wave-uniform)
  float acc[16];
#pragma unroll
  for (int kk = 0; kk < 16; ++kk) acc[kk] = 0.f;
  const float* cwb = conv_w + (q * 16) * CC;

  // logits over c in [0,128)
  for (int cc = 0; cc < 128; cc += 32) {
    float xv[32];
#pragma unroll
    for (int j = 0; j < 32; ++j) xv[j] = xh[cc + j][t];
#pragma unroll
    for (int kk = 0; kk < 16; ++kk) {
      const float* cw = cwb + kk * CC + cc;
#pragma unroll
      for (int j = 0; j < 32; ++j) acc[kk] = fmaf(cw[j], xv[j], acc[kk]);
    }
  }
  __syncthreads();

  // ---- store half 1, finish ssq / inv norm ----
#pragma unroll
  for (int j = 0; j < 8; ++j) {
    float4 v = r[j];
    ssq += v.x * v.x + v.y * v.y + v.z * v.z + v.w * v.w;
    int c = (lseg + 4 * j) * 4;
    xh[c + 0][lt] = v.x; xh[c + 1][lt] = v.y;
    xh[c + 2][lt] = v.z; xh[c + 3][lt] = v.w;
  }
  ssq += __shfl_xor(ssq, 1);
  ssq += __shfl_xor(ssq, 2);
  if (lseg == 0) invls[lt] = 1.0f / fmaxf(sqrtf(ssq), 1e-12f);
  __syncthreads();

  // logits over c in [128,256)
  for (int cc = 0; cc < 128; cc += 32) {
    float xv[32];
#pragma unroll
    for (int j = 0; j < 32; ++j) xv[j] = xh[cc + j][t];
#pragma unroll
    for (int kk = 0; kk < 16; ++kk) {
      const float* cw = cwb + kk * CC + 128 + cc;
#pragma unroll
      for (int j = 0; j < 32; ++j) acc[kk] = fmaf(cw[j], xv[j], acc[kk]);
    }
  }

  const float inv = invls[t];
#pragma unroll
  for (int kk = 0; kk < 16; ++kk) sal[q * 16 + kk][t] = acc[kk] * inv;
  __syncthreads();

  // softmax over 64 clusters (each of the 4 threads/token redundantly)
  float m = -3.4e38f;
  for (int k2 = 0; k2 < 64; ++k2) m = fmaxf(m, sal[k2][t]);
  float s = 0.f;
  for (int k2 = 0; k2 < 64; ++k2) s += __expf(sal[k2][t] - m);
  const float rs = 1.0f / s;

  float* sab = sa + ((size_t)b * KK + q * 16) * NN + n0 + t;
#pragma unroll
  for (int kk = 0; kk < 16; ++kk)
    sab[(size_t)kk * NN] = __expf(sal[q * 16 + kk][t] - m) * rs;
  if (q == 0) invn[b * NN + n0 + t] = inv;
}

// ============================================================
// K3: vlad partial GEMM: per (b, chunk of 256 n):
//     part[k][c] = sum_n sa[k][n] * (x[n][c]*invn[n]);  also sum_n sa
// block 256 thr, 8 sub-tiles of 32 n; grid (16, 32)
// ============================================================
__global__ __launch_bounds__(256) void k_vlad(
    const float* __restrict__ x, const float* __restrict__ sa,
    const float* __restrict__ invn, float* __restrict__ vpart,
    float* __restrict__ spart) {
  __shared__ __align__(16) float xs[32][260];  // [n][c]
  __shared__ __align__(16) float ss[32][68];   // [n][k]

  const int tid = threadIdx.x;
  const int ch = blockIdx.x;     // 0..15
  const int b  = blockIdx.y;     // 0..31
  const int cg = tid & 31;       // c-group
  const int kg = tid >> 5;       // k-group 0..7
  const int lnn = tid >> 3;      // load row 0..31
  const int lseg = tid & 7;      // 0..7

  float acc[8][8];
#pragma unroll
  for (int i = 0; i < 8; ++i)
#pragma unroll
    for (int j = 0; j < 8; ++j) acc[i][j] = 0.f;
  float ssum[8];
#pragma unroll
  for (int i = 0; i < 8; ++i) ssum[i] = 0.f;

  for (int tile = 0; tile < 8; ++tile) {
    const int nb = ch * 256 + tile * 32;

    // global loads into regs (before barrier)
    const float invv = invn[b * NN + nb + lnn];
    const float4* xr = reinterpret_cast<const float4*>(
        x + ((size_t)b * NN + nb + lnn) * CC);
    float4 v4[8];
#pragma unroll
    for (int j = 0; j < 8; ++j) v4[j] = xr[lseg + 8 * j];
    float sv8[8];
#pragma unroll
    for (int kk = 0; kk < 8; ++kk)
      sv8[kk] = sa[((size_t)b * KK + kg * 8 + kk) * NN + nb + (tid & 31)];

    __syncthreads();  // previous tile's readers are done

#pragma unroll
    for (int j = 0; j < 8; ++j) {
      float4 v = v4[j];
      v.x *= invv; v.y *= invv; v.z *= invv; v.w *= invv;
      *reinterpret_cast<float4*>(&xs[lnn][(lseg + 8 * j) * 4]) = v;
    }
#pragma unroll
    for (int kk = 0; kk < 8; ++kk) ss[tid & 31][kg * 8 + kk] = sv8[kk];
    __syncthreads();

#pragma unroll 2
    for (int n = 0; n < 32; ++n) {
      float4 s0 = *reinterpret_cast<const float4*>(&ss[n][kg * 8]);
      float4 s1 = *reinterpret_cast<const float4*>(&ss[n][kg * 8 + 4]);
      float4 x0 = *reinterpret_cast<const float4*>(&xs[n][cg * 8]);
      float4 x1 = *reinterpret_cast<const float4*>(&xs[n][cg * 8 + 4]);
      float sv[8] = {s0.x, s0.y, s0.z, s0.w, s1.x, s1.y, s1.z, s1.w};
      float xv[8] = {x0.x, x0.y, x0.z, x0.w, x1.x, x1.y, x1.z, x1.w};
#pragma unroll
      for (int i = 0; i < 8; ++i) {
#pragma unroll
        for (int j = 0; j < 8; ++j)
          acc[i][j] = fmaf(sv[i], xv[j], acc[i][j]);
        ssum[i] += sv[i];
      }
    }
  }

  const size_t obase = (((size_t)b * 16 + ch) * KK + kg * 8) * CC + cg * 8;
#pragma unroll
  for (int i = 0; i < 8; ++i) {
    float4 o0 = {acc[i][0], acc[i][1], acc[i][2], acc[i][3]};
    float4 o1 = {acc[i][4], acc[i][5], acc[i][6], acc[i][7]};
    *reinterpret_cast<float4*>(vpart + obase + (size_t)i * CC) = o0;
    *reinterpret_cast<float4*>(vpart + obase + (size_t)i * CC + 4) = o1;
  }
  if (cg == 0) {
#pragma unroll
    for (int i = 0; i < 8; ++i)
      spart[((size_t)b * 16 + ch) * KK + kg * 8 + i] = ssum[i];
  }
}

// ============================================================
// K4: reduce partials, subtract S*centroid, intra-norm, /8 (global norm)
// grid = B*K = 2048 blocks, 256 threads (c)
// ============================================================
__global__ __launch_bounds__(256) void k_vladnorm(
    const float* __restrict__ vpart, const float* __restrict__ spart,
    const float* __restrict__ cent, float* __restrict__ vladn) {
  const int b = blockIdx.x >> 6, k = blockIdx.x & 63;
  const int c = threadIdx.x;
  float v = 0.f, S = 0.f;
#pragma unroll
  for (int ch = 0; ch < 16; ++ch) {
    v += vpart[(((size_t)b * 16 + ch) * KK + k) * CC + c];
    S += spart[((size_t)b * 16 + ch) * KK + k];
  }
  v -= S * cent[k * CC + c];

  float ssq = v * v;
#pragma unroll
  for (int off = 32; off >= 1; off >>= 1) ssq += __shfl_xor(ssq, off);
  __shared__ float w4[4];
  if ((threadIdx.x & 63) == 0) w4[threadIdx.x >> 6] = ssq;
  __syncthreads();
  const float tot = w4[0] + w4[1] + w4[2] + w4[3];
  // intra-norm, then global norm over [K*C] is exactly 8 (64 unit rows)
  const float sc = 0.125f / fmaxf(sqrtf(tot), 1e-12f);
  vladn[(size_t)b * (KK * CC) + k * CC + c] = v * sc;
}

// ============================================================
// K5: hidden GEMM partials: out1[b][d] over i-slab of 64
// grid = 256 blocks (i-slabs), 256 threads (d)
// ============================================================
__global__ __launch_bounds__(256) void k_hidden(
    const float* __restrict__ vladn, const float* __restrict__ hw,
    float* __restrict__ k5p) {
  const int g = blockIdx.x, d = threadIdx.x;
  const int i0 = g * 64;
  float acc[32];
#pragma unroll
  for (int b2 = 0; b2 < 32; ++b2) acc[b2] = 0.f;
#pragma unroll 4
  for (int ii = 0; ii < 64; ++ii) {
    const float w = hw[(size_t)(i0 + ii) * DD + d];
#pragma unroll
    for (int b2 = 0; b2 < 32; ++b2)
      acc[b2] = fmaf(vladn[(size_t)b2 * (KK * CC) + i0 + ii], w, acc[b2]);
  }
#pragma unroll
  for (int b2 = 0; b2 < 32; ++b2)
    k5p[((size_t)g * 32 + b2) * DD + d] = acc[b2];
}

// ============================================================
// K6: reduce hidden partials -> out1[b][d]
// ============================================================
__global__ __launch_bounds__(256) void k_red1(
    const float* __restrict__ k5p, float* __restrict__ out1) {
  const int b = blockIdx.x, d = threadIdx.x;
  float s = 0.f;
  for (int g = 0; g < 256; ++g) s += k5p[((size_t)g * 32 + b) * DD + d];
  out1[b * DD + d] = s;
}

// ============================================================
// K7: BN -> gating GEMM -> BN -> sigmoid -> multiply
// grid = 32 blocks (8 output cols each), 256 threads
// ============================================================
__global__ __launch_bounds__(256) void k_final(
    const float* __restrict__ out1, const float* __restrict__ gw,
    const float* __restrict__ bn2g, const float* __restrict__ bn2b,
    const float* __restrict__ gbng, const float* __restrict__ gbnb,
    float* __restrict__ out) {
  __shared__ float yls[32][257];
  __shared__ float gls[32 * 9];
  const int tid = threadIdx.x;

  // stage 1: BN over batch for all 256 dims (redundant per block)
  {
    const int d = tid;
    float vals[32];
    float m = 0.f;
#pragma unroll
    for (int b5 = 0; b5 < 32; ++b5) { vals[b5] = out1[b5 * DD + d]; m += vals[b5]; }
    m *= (1.f / 32.f);
    float var = 0.f;
#pragma unroll
    for (int b5 = 0; b5 < 32; ++b5) { float tt = vals[b5] - m; var += tt * tt; }
    var *= (1.f / 32.f);
    const float sc = bn2g[d] / sqrtf(var + 1e-5f);
    const float sh = bn2b[d];
#pragma unroll
    for (int b5 = 0; b5 < 32; ++b5) yls[b5][d] = (vals[b5] - m) * sc + sh;
  }
  __syncthreads();

  // stage 2: gating GEMM for this block's 8 columns
  const int d2t = tid & 7, b4 = tid >> 3;
  const int d2 = blockIdx.x * 8 + d2t;
  float a = 0.f;
  for (int dd = 0; dd < 256; ++dd) a = fmaf(yls[b4][dd], gw[dd * DD + d2], a);
  gls[b4 * 9 + d2t] = a;
  __syncthreads();

  // stage 3: BN over batch + sigmoid + gate
  float m2 = 0.f;
#pragma unroll
  for (int b5 = 0; b5 < 32; ++b5) m2 += gls[b5 * 9 + d2t];
  m2 *= (1.f / 32.f);
  float v2 = 0.f;
#pragma unroll
  for (int b5 = 0; b5 < 32; ++b5) { float tt = gls[b5 * 9 + d2t] - m2; v2 += tt * tt; }
  v2 *= (1.f / 32.f);
  const float gn = (a - m2) / sqrtf(v2 + 1e-5f) * gbng[d2] + gbnb[d2];
  const float gate = 1.f / (1.f + __expf(-gn));
  out[b4 * DD + d2] = yls[b4][d2] * gate;
}

// ============================================================
extern "C" void kernel_launch(void* const* d_in, const int* in_sizes, int n_in,
                              void* d_out, int out_size, void* d_ws, size_t ws_size,
                              hipStream_t stream) {
  const float* x      = (const float*)d_in[0];
  const float* conv_w = (const float*)d_in[1];
  const float* cent   = (const float*)d_in[2];
  const float* hw     = (const float*)d_in[3];
  const float* gw     = (const float*)d_in[4];
  const float* bn2g   = (const float*)d_in[5];
  const float* bn2b   = (const float*)d_in[6];
  const float* gbng   = (const float*)d_in[7];
  const float* gbnb   = (const float*)d_in[8];

  float* ws    = (float*)d_ws;
  float* sa    = ws + SA_OFF;
  float* invn  = ws + INV_OFF;
  float* vpart = ws + VP_OFF;
  float* spart = ws + SP_OFF;
  float* vladn = ws + VN_OFF;
  float* out1  = ws + O1_OFF;
  float* k5p   = ws + K5_OFF;

  k_softmax<<<BB * (NN / 64), 256, 0, stream>>>(x, conv_w, sa, invn);
  k_vlad<<<dim3(16, BB), 256, 0, stream>>>(x, sa, invn, vpart, spart);
  k_vladnorm<<<BB * KK, 256, 0, stream>>>(vpart, spart, cent, vladn);
  k_hidden<<<256, 256, 0, stream>>>(vladn, hw, k5p);
  k_red1<<<BB, 256, 0, stream>>>(k5p, out1);
  k_final<<<32, 256, 0, stream>>>(out1, gw, bn2g, bn2b, gbng, gbnb,
                                  (float*)d_out);
}

// Round 4
// 370.155 us; speedup vs baseline: 1.5374x; 1.5374x over previous
//
#include <hip/hip_runtime.h>

#define BB 32
#define NN 4096
#define CC 256
#define KK 64
#define DD 256

// ---- workspace layout (in floats) ----
#define SA_OFF   ((size_t)0)                       // sa      [B][K][N]
#define INV_OFF  (SA_OFF  + (size_t)BB*KK*NN)      // invn    [B][N]
#define VP_OFF   (INV_OFF + (size_t)BB*NN)         // vpart   [B][16][K][C]
#define SP_OFF   (VP_OFF  + (size_t)BB*16*KK*CC)   // spart   [B][16][K]
#define VN_OFF   (SP_OFF  + (size_t)BB*16*KK)      // vladn   [B][K*C]
#define O1P_OFF  (VN_OFF  + (size_t)BB*KK*CC)      // o1p     [8][32][256]
#define K5_OFF   (O1P_OFF + (size_t)8*BB*DD)       // k5part  [256][32][256]

// ============================================================
// K1: per-token L2 norm + 1x1-conv logits + softmax over K
// block = 256 thr; 256 tokens/block; grid = B * N/256 = 512
// conv_w staged in LDS (no uniform-VMEM storm); 8t x 8k reg tile.
// ============================================================
__global__ __launch_bounds__(256) void k_softmax(
    const float* __restrict__ x, const float* __restrict__ conv_w,
    float* __restrict__ sa, float* __restrict__ invn) {
  __shared__ union {
    struct { float xs[16][264]; float wls[16][72]; } g;   // GEMM staging
    struct { float mxb[8][256]; float smb[8][256]; } r;   // softmax reduce
  } u;
  __shared__ float invls[256];

  const int tid = threadIdx.x;
  const int b  = blockIdx.x >> 4;
  const int n0 = (blockIdx.x & 15) * 256;

  // staging roles
  const int wk = tid >> 2, wseg = tid & 3;     // conv_w: 64 k x 4 segs
  // compute roles: thread owns tokens {tg+32i} and k in [kg*8, kg*8+8)
  const int tg = tid & 31, kg = tid >> 5;

  const float4* xrow = reinterpret_cast<const float4*>(
      x + ((size_t)b * NN + n0 + tid) * CC);
  const float4* wrow = reinterpret_cast<const float4*>(conv_w + (size_t)wk * CC);

  float acc[8][8];
#pragma unroll
  for (int i = 0; i < 8; ++i)
#pragma unroll
    for (int j = 0; j < 8; ++j) acc[i][j] = 0.f;
  float ssq = 0.f;

  float4 xr[4], wr;
#pragma unroll
  for (int j = 0; j < 4; ++j) xr[j] = xrow[j];
  wr = wrow[wseg];

  for (int ch = 0; ch < 16; ++ch) {
    __syncthreads();   // previous chunk's LDS readers done
#pragma unroll
    for (int j = 0; j < 4; ++j) {
      float4 v = xr[j];
      ssq += v.x * v.x + v.y * v.y + v.z * v.z + v.w * v.w;
      u.g.xs[j * 4 + 0][tid] = v.x;
      u.g.xs[j * 4 + 1][tid] = v.y;
      u.g.xs[j * 4 + 2][tid] = v.z;
      u.g.xs[j * 4 + 3][tid] = v.w;
    }
    {
      float4 v = wr;
      u.g.wls[wseg * 4 + 0][wk] = v.x;
      u.g.wls[wseg * 4 + 1][wk] = v.y;
      u.g.wls[wseg * 4 + 2][wk] = v.z;
      u.g.wls[wseg * 4 + 3][wk] = v.w;
    }
    if (ch < 15) {  // prefetch next chunk (in flight during compute)
#pragma unroll
      for (int j = 0; j < 4; ++j) xr[j] = xrow[(ch + 1) * 4 + j];
      wr = wrow[(ch + 1) * 4 + wseg];
    }
    __syncthreads();

#pragma unroll 2
    for (int cl = 0; cl < 16; ++cl) {
      float xv[8];
#pragma unroll
      for (int i = 0; i < 8; ++i) xv[i] = u.g.xs[cl][tg + 32 * i];
      float4 w0 = *reinterpret_cast<const float4*>(&u.g.wls[cl][kg * 8]);
      float4 w1 = *reinterpret_cast<const float4*>(&u.g.wls[cl][kg * 8 + 4]);
      float wv[8] = {w0.x, w0.y, w0.z, w0.w, w1.x, w1.y, w1.z, w1.w};
#pragma unroll
      for (int i = 0; i < 8; ++i)
#pragma unroll
        for (int j = 0; j < 8; ++j)
          acc[i][j] = fmaf(xv[i], wv[j], acc[i][j]);
    }
  }

  // per-token inverse norm (each thread staged its own token's 256 c)
  const float inv = 1.0f / fmaxf(sqrtf(ssq), 1e-12f);
  invls[tid] = inv;
  invn[b * NN + n0 + tid] = inv;
  __syncthreads();   // GEMM LDS dead; invls visible

  float inv_t[8], M[8], S[8];
#pragma unroll
  for (int i = 0; i < 8; ++i) inv_t[i] = invls[tg + 32 * i];
#pragma unroll
  for (int i = 0; i < 8; ++i) {
    float m = -3.4e38f;
#pragma unroll
    for (int j = 0; j < 8; ++j) {
      acc[i][j] *= inv_t[i];
      m = fmaxf(m, acc[i][j]);
    }
    u.r.mxb[kg][tg + 32 * i] = m;
  }
  __syncthreads();
#pragma unroll
  for (int i = 0; i < 8; ++i) {
    float m = u.r.mxb[0][tg + 32 * i];
#pragma unroll
    for (int kk = 1; kk < 8; ++kk) m = fmaxf(m, u.r.mxb[kk][tg + 32 * i]);
    M[i] = m;
  }
#pragma unroll
  for (int i = 0; i < 8; ++i) {
    float s = 0.f;
#pragma unroll
    for (int j = 0; j < 8; ++j) {
      acc[i][j] = __expf(acc[i][j] - M[i]);
      s += acc[i][j];
    }
    u.r.smb[kg][tg + 32 * i] = s;
  }
  __syncthreads();
#pragma unroll
  for (int i = 0; i < 8; ++i) {
    float s = u.r.smb[0][tg + 32 * i];
#pragma unroll
    for (int kk = 1; kk < 8; ++kk) s += u.r.smb[kk][tg + 32 * i];
    S[i] = 1.0f / s;
  }
  // sa[b][k][n]: scalar stores, half-wave-contiguous over tokens
#pragma unroll
  for (int j = 0; j < 8; ++j) {
    float* dst = sa + ((size_t)b * KK + kg * 8 + j) * NN + n0 + tg;
#pragma unroll
    for (int i = 0; i < 8; ++i) dst[32 * i] = acc[i][j] * S[i];
  }
}

// ============================================================
// K3: vlad partial GEMM: per (b, chunk of 256 n):
//     part[k][c] = sum_n sa[k][n] * (x[n][c]*invn[n]);  also sum_n sa
// ============================================================
__global__ __launch_bounds__(256) void k_vlad(
    const float* __restrict__ x, const float* __restrict__ sa,
    const float* __restrict__ invn, float* __restrict__ vpart,
    float* __restrict__ spart) {
  __shared__ __align__(16) float xs[32][260];  // [n][c]
  __shared__ __align__(16) float ss[32][68];   // [n][k]

  const int tid = threadIdx.x;
  const int ch = blockIdx.x;     // 0..15
  const int b  = blockIdx.y;     // 0..31
  const int cg = tid & 31;       // c-group
  const int kg = tid >> 5;       // k-group 0..7
  const int lnn = tid >> 3;      // load row 0..31
  const int lseg = tid & 7;      // 0..7

  float acc[8][8];
#pragma unroll
  for (int i = 0; i < 8; ++i)
#pragma unroll
    for (int j = 0; j < 8; ++j) acc[i][j] = 0.f;
  float ssum[8];
#pragma unroll
  for (int i = 0; i < 8; ++i) ssum[i] = 0.f;

  for (int tile = 0; tile < 8; ++tile) {
    const int nb = ch * 256 + tile * 32;

    const float invv = invn[b * NN + nb + lnn];
    const float4* xr = reinterpret_cast<const float4*>(
        x + ((size_t)b * NN + nb + lnn) * CC);
    float4 v4[8];
#pragma unroll
    for (int j = 0; j < 8; ++j) v4[j] = xr[lseg + 8 * j];
    float sv8[8];
#pragma unroll
    for (int kk = 0; kk < 8; ++kk)
      sv8[kk] = sa[((size_t)b * KK + kg * 8 + kk) * NN + nb + (tid & 31)];

    __syncthreads();

#pragma unroll
    for (int j = 0; j < 8; ++j) {
      float4 v = v4[j];
      v.x *= invv; v.y *= invv; v.z *= invv; v.w *= invv;
      *reinterpret_cast<float4*>(&xs[lnn][(lseg + 8 * j) * 4]) = v;
    }
#pragma unroll
    for (int kk = 0; kk < 8; ++kk) ss[tid & 31][kg * 8 + kk] = sv8[kk];
    __syncthreads();

#pragma unroll 2
    for (int n = 0; n < 32; ++n) {
      float4 s0 = *reinterpret_cast<const float4*>(&ss[n][kg * 8]);
      float4 s1 = *reinterpret_cast<const float4*>(&ss[n][kg * 8 + 4]);
      float4 x0 = *reinterpret_cast<const float4*>(&xs[n][cg * 8]);
      float4 x1 = *reinterpret_cast<const float4*>(&xs[n][cg * 8 + 4]);
      float sv[8] = {s0.x, s0.y, s0.z, s0.w, s1.x, s1.y, s1.z, s1.w};
      float xv[8] = {x0.x, x0.y, x0.z, x0.w, x1.x, x1.y, x1.z, x1.w};
#pragma unroll
      for (int i = 0; i < 8; ++i) {
#pragma unroll
        for (int j = 0; j < 8; ++j)
          acc[i][j] = fmaf(sv[i], xv[j], acc[i][j]);
        ssum[i] += sv[i];
      }
    }
  }

  const size_t obase = (((size_t)b * 16 + ch) * KK + kg * 8) * CC + cg * 8;
#pragma unroll
  for (int i = 0; i < 8; ++i) {
    float4 o0 = {acc[i][0], acc[i][1], acc[i][2], acc[i][3]};
    float4 o1 = {acc[i][4], acc[i][5], acc[i][6], acc[i][7]};
    *reinterpret_cast<float4*>(vpart + obase + (size_t)i * CC) = o0;
    *reinterpret_cast<float4*>(vpart + obase + (size_t)i * CC + 4) = o1;
  }
  if (cg == 0) {
#pragma unroll
    for (int i = 0; i < 8; ++i)
      spart[((size_t)b * 16 + ch) * KK + kg * 8 + i] = ssum[i];
  }
}

// ============================================================
// K4: reduce partials, subtract S*centroid, intra-norm, /8
// ============================================================
__global__ __launch_bounds__(256) void k_vladnorm(
    const float* __restrict__ vpart, const float* __restrict__ spart,
    const float* __restrict__ cent, float* __restrict__ vladn) {
  const int b = blockIdx.x >> 6, k = blockIdx.x & 63;
  const int c = threadIdx.x;
  float v = 0.f, S = 0.f;
#pragma unroll
  for (int ch = 0; ch < 16; ++ch) {
    v += vpart[(((size_t)b * 16 + ch) * KK + k) * CC + c];
    S += spart[((size_t)b * 16 + ch) * KK + k];
  }
  v -= S * cent[k * CC + c];

  float ssq = v * v;
#pragma unroll
  for (int off = 32; off >= 1; off >>= 1) ssq += __shfl_xor(ssq, off);
  __shared__ float w4[4];
  if ((threadIdx.x & 63) == 0) w4[threadIdx.x >> 6] = ssq;
  __syncthreads();
  const float tot = w4[0] + w4[1] + w4[2] + w4[3];
  const float sc = 0.125f / fmaxf(sqrtf(tot), 1e-12f);
  vladn[(size_t)b * (KK * CC) + k * CC + c] = v * sc;
}

// ============================================================
// K5: hidden GEMM partials. grid (128 islabs, 2 d-halves)
// thread: one d, 64-i strip, 32 b accumulators; vladn via float4
// ============================================================
__global__ __launch_bounds__(256) void k_hidden(
    const float* __restrict__ vladn, const float* __restrict__ hw,
    float* __restrict__ k5p) {
  const int islab = blockIdx.x;           // 0..127
  const int dh = blockIdx.y;              // 0..1
  const int tid = threadIdx.x;
  const int d = dh * 128 + (tid & 127);
  const int ig = tid >> 7;
  const int ibase = islab * 128 + ig * 64;
  const int p = islab * 2 + ig;

  float w[64];
#pragma unroll 8
  for (int ii = 0; ii < 64; ++ii)
    w[ii] = hw[(size_t)(ibase + ii) * DD + d];

#pragma unroll 4
  for (int b2 = 0; b2 < 32; ++b2) {
    const float4* vp = reinterpret_cast<const float4*>(
        vladn + (size_t)b2 * (KK * CC) + ibase);
    float a = 0.f;
#pragma unroll
    for (int q = 0; q < 16; ++q) {
      float4 v = vp[q];
      a = fmaf(v.x, w[q * 4 + 0], a);
      a = fmaf(v.y, w[q * 4 + 1], a);
      a = fmaf(v.z, w[q * 4 + 2], a);
      a = fmaf(v.w, w[q * 4 + 3], a);
    }
    k5p[((size_t)p * 32 + b2) * DD + d] = a;
  }
}

// ============================================================
// K6: reduce 256 hidden partials -> o1p[8][32][256]
// ============================================================
__global__ __launch_bounds__(256) void k_red1(
    const float* __restrict__ k5p, float* __restrict__ o1p) {
  const int b = blockIdx.x & 31, ch = blockIdx.x >> 5, d = threadIdx.x;
  float s = 0.f;
#pragma unroll 4
  for (int p = ch * 32; p < ch * 32 + 32; ++p)
    s += k5p[((size_t)p * 32 + b) * DD + d];
  o1p[((size_t)ch * 32 + b) * DD + d] = s;
}

// ============================================================
// K7: BN -> gating GEMM -> BN -> sigmoid -> multiply
// ============================================================
__global__ __launch_bounds__(256) void k_final(
    const float* __restrict__ o1p, const float* __restrict__ gw,
    const float* __restrict__ bn2g, const float* __restrict__ bn2b,
    const float* __restrict__ gbng, const float* __restrict__ gbnb,
    float* __restrict__ out) {
  __shared__ float yls[32][257];
  __shared__ float gls[32 * 9];
  const int tid = threadIdx.x;

  {
    const int d = tid;
    float vals[32];
    float m = 0.f;
#pragma unroll
    for (int b5 = 0; b5 < 32; ++b5) {
      float v = 0.f;
#pragma unroll
      for (int c2 = 0; c2 < 8; ++c2) v += o1p[((size_t)c2 * 32 + b5) * DD + d];
      vals[b5] = v; m += v;
    }
    m *= (1.f / 32.f);
    float var = 0.f;
#pragma unroll
    for (int b5 = 0; b5 < 32; ++b5) { float tt = vals[b5] - m; var += tt * tt; }
    var *= (1.f / 32.f);
    const float sc = bn2g[d] / sqrtf(var + 1e-5f);
    const float sh = bn2b[d];
#pragma unroll
    for (int b5 = 0; b5 < 32; ++b5) yls[b5][d] = (vals[b5] - m) * sc + sh;
  }
  __syncthreads();

  const int d2t = tid & 7, b4 = tid >> 3;
  const int d2 = blockIdx.x * 8 + d2t;
  float a = 0.f;
  for (int dd = 0; dd < 256; ++dd) a = fmaf(yls[b4][dd], gw[dd * DD + d2], a);
  gls[b4 * 9 + d2t] = a;
  __syncthreads();

  float m2 = 0.f;
#pragma unroll
  for (int b5 = 0; b5 < 32; ++b5) m2 += gls[b5 * 9 + d2t];
  m2 *= (1.f / 32.f);
  float v2 = 0.f;
#pragma unroll
  for (int b5 = 0; b5 < 32; ++b5) { float tt = gls[b5 * 9 + d2t] - m2; v2 += tt * tt; }
  v2 *= (1.f / 32.f);
  const float gn = (a - m2) / sqrtf(v2 + 1e-5f) * gbng[d2] + gbnb[d2];
  const float gate = 1.f / (1.f + __expf(-gn));
  out[b4 * DD + d2] = yls[b4][d2] * gate;
}

// ============================================================
extern "C" void kernel_launch(void* const* d_in, const int* in_sizes, int n_in,
                              void* d_out, int out_size, void* d_ws, size_t ws_size,
                              hipStream_t stream) {
  const float* x      = (const float*)d_in[0];
  const float* conv_w = (const float*)d_in[1];
  const float* cent   = (const float*)d_in[2];
  const float* hw     = (const float*)d_in[3];
  const float* gw     = (const float*)d_in[4];
  const float* bn2g   = (const float*)d_in[5];
  const float* bn2b   = (const float*)d_in[6];
  const float* gbng   = (const float*)d_in[7];
  const float* gbnb   = (const float*)d_in[8];

  float* ws    = (float*)d_ws;
  float* sa    = ws + SA_OFF;
  float* invn  = ws + INV_OFF;
  float* vpart = ws + VP_OFF;
  float* spart = ws + SP_OFF;
  float* vladn = ws + VN_OFF;
  float* o1p   = ws + O1P_OFF;
  float* k5p   = ws + K5_OFF;

  k_softmax<<<BB * (NN / 256), 256, 0, stream>>>(x, conv_w, sa, invn);
  k_vlad<<<dim3(16, BB), 256, 0, stream>>>(x, sa, invn, vpart, spart);
  k_vladnorm<<<BB * KK, 256, 0, stream>>>(vpart, spart, cent, vladn);
  k_hidden<<<dim3(128, 2), 256, 0, stream>>>(vladn, hw, k5p);
  k_red1<<<256, 256, 0, stream>>>(k5p, o1p);
  k_final<<<32, 256, 0, stream>>>(o1p, gw, bn2g, bn2b, gbng, gbnb,
                                  (float*)d_out);
}